// Round 8
// baseline (584.776 us; speedup 1.0000x reference)
//
#include <hip/hip_runtime.h>
#include <hip/hip_bf16.h>
#include <cstdint>
#include <cstddef>

typedef __hip_bfloat16 bf16;
typedef __attribute__((ext_vector_type(8))) short short8;
typedef __attribute__((ext_vector_type(4))) float f32x4;
typedef __attribute__((ext_vector_type(2))) float f32x2;

#define NE 65536
#define NN 131072
#define TLEN 50
#define NB 4096
#define ACT 53
#define ROWF 120   // padded accumulator row (16B-aligned float4 rows)

// ---------------- workspace layout (float units) ----------------
static constexpr size_t SZ_ACC      = (size_t)NN * ROWF;
static constexpr size_t OFF_IN_ACC  = 0;
static constexpr size_t OFF_OUT_ACC = OFF_IN_ACC + SZ_ACC;
static constexpr size_t OFF_CNT_IN  = OFF_OUT_ACC + SZ_ACC;
static constexpr size_t OFF_CNT_OUT = OFF_CNT_IN + NN;
static constexpr size_t ZERO_FLOATS = OFF_CNT_OUT + NN;          // memset region
// bf16 tables (float-slot units; 2 bf16 per float slot)
static constexpr size_t OFF_ZXF     = ZERO_FLOATS;               // [2][8][64][8] bf16 (0.5-scaled i/f/o)
static constexpr size_t OFF_WFRAG   = OFF_ZXF + 4096;            // [2][8][64][8] bf16 (K-permuted, 0.5-scaled i/f/o)
static constexpr size_t OFF_B1      = OFF_WFRAG + 4096;          // [8][10][64][8] bf16, k-mapped w/ pad cols
static constexpr size_t OFF_B2      = OFF_B1 + 20480;            // [4][4][64][8] bf16
static constexpr size_t OFF_B3      = OFF_B2 + 4096;             // [2][2][64][8] bf16
static constexpr size_t OFF_P1B     = OFF_B3 + 1024;             // fp32
static constexpr size_t OFF_P2B     = OFF_P1B + 128;
static constexpr size_t OFF_P3B     = OFF_P2B + 64;
static constexpr size_t OFF_P4W     = OFF_P3B + 32;
static constexpr size_t OFF_P4B     = OFF_P4W + 32;
static constexpr size_t OFF_V1W     = OFF_P4B + 32;
static constexpr size_t OFF_V1B     = OFF_V1W + 9248;
static constexpr size_t OFF_V2W     = OFF_V1B + 32;
static constexpr size_t OFF_V2B     = OFF_V2W + 32;
static constexpr size_t OFF_FLAG    = OFF_V2B + 32;              // int dtype flag

__device__ __forceinline__ unsigned short f2bf(float f) {      // RNE fp32->bf16 bits
  unsigned u = __float_as_uint(f);
  return (unsigned short)((u + 0x7fffu + ((u >> 16) & 1u)) >> 16);
}
__device__ __forceinline__ float bf2f(short b) {
  return __uint_as_float(((unsigned)(unsigned short)b) << 16);
}
__device__ __forceinline__ f32x2 fma2(f32x2 a, f32x2 b, f32x2 c) {
  return __builtin_elementwise_fma(a, b, c);
}
// packed tanh approx: med3 clamp + quartic-in-u poly (|err|<=~0.04, bounded)
__device__ __forceinline__ f32x2 tp2(f32x2 x) {
  f32x2 t;
  t.x = __builtin_amdgcn_fmed3f(x.x, -2.6f, 2.6f);
  t.y = __builtin_amdgcn_fmed3f(x.y, -2.6f, 2.6f);
  f32x2 u = t * t;
  f32x2 p = fma2(u, (f32x2){0.000961802f, 0.000961802f}, (f32x2){-0.01541917f, -0.01541917f});
  p = fma2(u, p, (f32x2){0.0940697f, 0.0940697f});
  p = fma2(u, p, (f32x2){-0.320066f, -0.320066f});
  p = fma2(u, p, (f32x2){1.0f, 1.0f});
  return t * p;
}

template<bool BF>
__device__ __forceinline__ float ldf(const void* p, size_t i) {
  if constexpr (BF) return __bfloat162float(((const bf16*)p)[i]);
  else              return ((const float*)p)[i];
}
template<bool BF>
__device__ __forceinline__ void stf(void* p, size_t i, float v) {
  if constexpr (BF) ((bf16*)p)[i] = __float2bfloat16(v);
  else              ((float*)p)[i] = v;
}

// ---------------- dtype detect: low 16 bits of x words ----------------
__global__ void detect_kernel(const unsigned int* __restrict__ xw, int* __restrict__ flag) {
  int lane = threadIdx.x;
  int cnt = 0;
  #pragma unroll
  for (int i = 0; i < 4; ++i) {
    unsigned w = xw[lane * 4 + i];
    unsigned e = (w >> 7) & 0xFFu;
    cnt += (e >= 100u && e <= 150u) ? 1 : 0;
  }
  #pragma unroll
  for (int off = 32; off; off >>= 1) cnt += __shfl_down(cnt, off);
  if (lane == 0) *flag = (cnt >= 192) ? 1 : 0;   // 1 = bf16 inputs
}

// ---------------- param prep ----------------
struct PrepPtrs {
  const void *emb, *wihf, *whhf, *bfw, *wihb, *whhb, *bbw;
  const void *p1w, *p1b, *p2w, *p2b, *p3w, *p3b, *p4w, *p4b;
  const void *v1w, *v1b, *v2w, *v2b;
};

template<bool BF>
__device__ __forceinline__ void prep_body(int idx, const PrepPtrs P, float* __restrict__ ws) {
  if (idx < 8192) {
    // ZX B-frag (bias folded). 0.5-scaled for i/f/o tiles (T!=4,5) so z arrives as z/2.
    int d = idx >> 12, r = idx & 4095;
    int T = r >> 9, L = (r >> 3) & 63, jj = r & 7;
    int n = L & 15, q = L >> 4;
    int k = q*8 + jj, col = T*16 + n;
    float s = 0.f;
    if (k < 20) {
      s = ldf<BF>(d ? P.bbw : P.bfw, col);
      const void* wih = d ? P.wihb : P.wihf;
      #pragma unroll
      for (int kk = 0; kk < 8; ++kk)
        s += ldf<BF>(wih, col*8 + kk) * ldf<BF>(P.emb, k*8 + kk);
      if (T != 4 && T != 5) s *= 0.5f;
    }
    ((short*)(ws + OFF_ZXF))[idx] = (short)f2bf(s);
    return;
  }
  idx -= 8192;
  if (idx < 8192) {
    // Whh B-frag, K-PERMUTED (k -> u=(k>>1)+16*(k&1)), 0.5-scaled for i/f/o tiles
    int d = idx >> 12, r = idx & 4095;
    int T = r >> 9, L = (r >> 3) & 63, jj = r & 7;
    int n = L & 15, q = L >> 4;
    int k = q*8 + jj;
    int u = (k >> 1) + 16*(k & 1);
    float v = ldf<BF>(d ? P.whhb : P.whhf, (size_t)(T*16 + n) * 32 + u);
    if (T != 4 && T != 5) v *= 0.5f;
    ((short*)(ws + OFF_WFRAG))[d*4096 + r] = (short)f2bf(v);
    return;
  }
  idx -= 8192;
  if (idx < 40960) {
    // p1w B-frags: [NT=8][KT=10][lane][8]; xc col map: x 0..54, pad 55, in 56..172,
    // pad 173, out 174..290, pad 291+  (pad rows zero)
    int r = idx;
    int NTKT = r >> 9, L = (r >> 3) & 63, j = r & 7;
    int NT = NTKT / 10, KT = NTKT - NT * 10;
    int n = L & 15, q = L >> 4;
    int k = KT*32 + q*8 + j, col = NT*16 + n;
    int krow = -1;
    if (k < 55) krow = k;
    else if (k > 55 && k < 173) krow = k - 1;
    else if (k > 173 && k < 291) krow = k - 2;
    float v = (krow >= 0) ? ldf<BF>(P.p1w, (size_t)krow * 128 + col) : 0.f;
    ((short*)(ws + OFF_B1))[r] = (short)f2bf(v);
    return;
  }
  idx -= 40960;
  if (idx < 8192) {      // p2w B-frags: [NT=4][KT=4][lane][8]
    int r = idx;
    int NTKT = r >> 9, L = (r >> 3) & 63, j = r & 7;
    int NT = NTKT >> 2, KT = NTKT & 3;
    int n = L & 15, q = L >> 4;
    int k = KT*32 + q*8 + j, col = NT*16 + n;
    ((short*)(ws + OFF_B2))[r] = (short)f2bf(ldf<BF>(P.p2w, (size_t)k * 64 + col));
    return;
  }
  idx -= 8192;
  if (idx < 2048) {      // p3w B-frags: [NT=2][KT=2][lane][8]
    int r = idx;
    int NTKT = r >> 9, L = (r >> 3) & 63, j = r & 7;
    int NT = NTKT >> 1, KT = NTKT & 1;
    int n = L & 15, q = L >> 4;
    int k = KT*32 + q*8 + j, col = NT*16 + n;
    ((short*)(ws + OFF_B3))[r] = (short)f2bf(ldf<BF>(P.p3w, (size_t)k * 32 + col));
    return;
  }
  idx -= 2048;
  #define CPY(src, off, n) if (idx < (n)) { ws[(off) + idx] = ldf<BF>(src, idx); return; } idx -= (n);
  CPY(P.p1b, OFF_P1B, 128)
  CPY(P.p2b, OFF_P2B, 64)
  CPY(P.p3b, OFF_P3B, 32)
  CPY(P.p4w, OFF_P4W, 32)
  CPY(P.p4b, OFF_P4B, 1)
  CPY(P.v1w, OFF_V1W, 9248)
  CPY(P.v1b, OFF_V1B, 32)
  CPY(P.v2w, OFF_V2W, 32)
  CPY(P.v2b, OFF_V2B, 1)
  #undef CPY
}

__global__ void prep_kernel(const int* __restrict__ flag, const PrepPtrs P, float* __restrict__ ws) {
  int idx = blockIdx.x * 256 + threadIdx.x;
  if (*flag) prep_body<true>(idx, P, ws);
  else       prep_body<false>(idx, P, ws);
}

// ---------------- bi-LSTM via MFMA + scatter-mean accumulate ----------------
// Direction-split blocks; packed-f32 gate math (v_pk_fma_f32), med3 clamps,
// 0.5 sigmoid scaling folded into weights. z = onehot(tok)@ZX + H@Whh^T.
template<bool BF>
__device__ __forceinline__ void lstm_body(
    short (*tk_s)[800], short (*h_s)[640],
    const int* __restrict__ tokens, const int* __restrict__ eidx,
    const void* __restrict__ src_num, const void* __restrict__ tgt_num,
    float* __restrict__ ws)
{
  float* in_acc  = ws + OFF_IN_ACC;
  float* out_acc = ws + OFF_OUT_ACC;
  float* cnt_in  = ws + OFF_CNT_IN;
  float* cnt_out = ws + OFF_CNT_OUT;
  const short* wfp = (const short*)(ws + OFF_WFRAG);
  const short* zxp = (const short*)(ws + OFF_ZXF);

  const int tid  = threadIdx.x;
  const int w    = tid >> 6;
  const int lane = tid & 63;
  const int n    = lane & 15;
  const int quad = lane >> 4;
  const int d    = blockIdx.x & 1;
  const int ebase = (blockIdx.x >> 1) * 64 + w * 16;

  for (int i = lane; i < 16 * TLEN; i += 64) {
    int e = i / TLEN, t = i - e * TLEN;
    tk_s[w][t * 16 + e] = (short)tokens[(size_t)(ebase + e) * TLEN + t];
  }
  __syncthreads();

  short8 wfr[8], zxfr[8];
  #pragma unroll
  for (int T = 0; T < 8; ++T) {
    wfr[T]  = *(const short8*)(wfp + d*4096 + T*512 + lane*8);
    zxfr[T] = *(const short8*)(zxp + d*4096 + T*512 + lane*8);
  }
  for (int i = lane; i < 320; i += 64) ((int*)h_s[w])[i] = 0;

  f32x2 c2_[4], accm2[4];
  #pragma unroll
  for (int r = 0; r < 4; ++r) { c2_[r] = (f32x2){0.f, 0.f}; accm2[r] = (f32x2){0.f, 0.f}; }

  const f32x4 zeroC = {0.f, 0.f, 0.f, 0.f};

  for (int t = 0; t < TLEN; ++t) {
    const int tt = d ? (TLEN - 1 - t) : t;
    const int tok = (int)tk_s[w][tt * 16 + n];

    int4 dwv;
    {
      int k0 = quad * 8;
      int v0 = (tok == k0    ) ? 0x3F80 : 0; v0 = (tok == k0 + 1) ? 0x3F800000 : v0;
      int v1 = (tok == k0 + 2) ? 0x3F80 : 0; v1 = (tok == k0 + 3) ? 0x3F800000 : v1;
      int v2 = (tok == k0 + 4) ? 0x3F80 : 0; v2 = (tok == k0 + 5) ? 0x3F800000 : v2;
      int v3 = (tok == k0 + 6) ? 0x3F80 : 0; v3 = (tok == k0 + 7) ? 0x3F800000 : v3;
      dwv = (int4){v0, v1, v2, v3};
    }
    short8 af2 = *reinterpret_cast<short8*>(&dwv);
    short8 af = *(const short8*)&h_s[w][n * 40 + quad * 8];

    f32x4 acc4[8];
    #pragma unroll
    for (int T = 0; T < 8; ++T)
      acc4[T] = __builtin_amdgcn_mfma_f32_16x16x32_bf16(af2, zxfr[T], zeroC, 0, 0, 0);
    #pragma unroll
    for (int T = 0; T < 8; ++T)
      acc4[T] = __builtin_amdgcn_mfma_f32_16x16x32_bf16(af, wfr[T], acc4[T], 0, 0, 0);

    // packed gates; zi/zf/zo arrive pre-scaled (z/2), zg unscaled
    #pragma unroll
    for (int r = 0; r < 4; ++r) {
      f32x2 zi = {acc4[0][r], acc4[1][r]};
      f32x2 zf = {acc4[2][r], acc4[3][r]};
      f32x2 zg = {acc4[4][r], acc4[5][r]};
      f32x2 zo = {acc4[6][r], acc4[7][r]};
      f32x2 si = tp2(zi);
      f32x2 sf = tp2(zf);
      f32x2 tg = tp2(zg);
      f32x2 so = tp2(zo);
      f32x2 cb = fma2(sf, c2_[r], c2_[r]);   // (1+sf)*c
      f32x2 db = fma2(si, tg, tg);           // (1+si)*tg
      f32x2 cv = (cb + db) * 0.5f;
      c2_[r] = cv;
      f32x2 tc = tp2(cv);
      f32x2 hv = fma2(so, tc, tc) * 0.5f;    // 0.5*(1+so)*tanh(c)
      accm2[r] += hv;
      unsigned pk = __builtin_amdgcn_perm(__float_as_uint(hv.y), __float_as_uint(hv.x), 0x07060302u);
      *(unsigned*)&h_s[w][(quad*4 + r) * 40 + 2*n] = pk;
    }
  }

  // scatter this direction's mean into feature slots [53+32d, 85+32d)
  const int fb = 53 + 32 * d;
  #pragma unroll
  for (int r = 0; r < 4; ++r) {
    int e  = ebase + quad * 4 + r;
    size_t so = (size_t)eidx[e] * ROWF;
    size_t to = (size_t)eidx[NE + e] * ROWF;
    float m0 = accm2[r].x * 0.02f;
    float m1 = accm2[r].y * 0.02f;
    atomicAdd(out_acc + so + fb + n,      m0);
    atomicAdd(out_acc + so + fb + n + 16, m1);
    atomicAdd(in_acc  + to + fb + n,      m0);
    atomicAdd(in_acc  + to + fb + n + 16, m1);
  }
  if (d == 0) {
    for (int i = lane; i < 16 * 53; i += 64) {
      int e = i / 53, f = i - e * 53;
      int ge = ebase + e;
      atomicAdd(out_acc + (size_t)eidx[ge] * ROWF + f,      ldf<BF>(tgt_num, (size_t)ge * 53 + f));
      atomicAdd(in_acc  + (size_t)eidx[NE + ge] * ROWF + f, ldf<BF>(src_num, (size_t)ge * 53 + f));
    }
    if (lane < 16) {
      int ge = ebase + lane;
      atomicAdd(cnt_out + eidx[ge], 1.f);
      atomicAdd(cnt_in  + eidx[NE + ge], 1.f);
    }
  }
}

__global__ __launch_bounds__(256) void lstm_kernel(
    const int* __restrict__ flag,
    const int* __restrict__ tokens, const int* __restrict__ eidx,
    const void* __restrict__ src_num, const void* __restrict__ tgt_num,
    float* __restrict__ ws)
{
  __shared__ short tk_s[4][800];
  __shared__ short h_s[4][640];
  if (*flag) lstm_body<true>(tk_s, h_s, tokens, eidx, src_num, tgt_num, ws);
  else       lstm_body<false>(tk_s, h_s, tokens, eidx, src_num, tgt_num, ws);
}

// ---------------- fused node-MLP (MFMA) + graph pool + v head + log_softmax ----------------
// Block = 128 threads (2 waves) = 32 nodes = 1 graph. ~22.7 KB LDS -> 7 blocks/CU.
// xc cols: x 0..54, pad55, in 56..172, pad173, out 174..290, zero 291..319.
template<bool BF>
__device__ __forceinline__ void pi_body(
    short* __restrict__ xc, float* __restrict__ rn, float* __restrict__ sg,
    float* __restrict__ pib, float* __restrict__ vb, float* __restrict__ mls,
    const void* __restrict__ x, float* __restrict__ ws, void* __restrict__ out)
{
  const float* in_acc  = ws + OFF_IN_ACC;
  const float* out_acc = ws + OFF_OUT_ACC;
  const float* cnt_in  = ws + OFF_CNT_IN;
  const float* cnt_out = ws + OFF_CNT_OUT;
  const float* p1b = ws + OFF_P1B;
  const float* p2b = ws + OFF_P2B;
  const float* p3b = ws + OFF_P3B;
  const float* p4w = ws + OFF_P4W;
  const float* v1w = ws + OFF_V1W;
  const float* v1b = ws + OFF_V1B;
  const float* v2w = ws + OFF_V2W;
  const float p4b0 = ws[OFF_P4B];
  const float v2b0 = ws[OFF_V2B];

  const int tid = threadIdx.x;
  const int w = tid >> 6, lane = tid & 63;
  const int nn = lane & 15, q = lane >> 4;
  const int nbase = blockIdx.x * 32;

  // phase 0: per-node reciprocals (32 nodes)
  if (tid < 64) {
    int n = tid >> 1;
    float c = (tid & 1) ? cnt_out[nbase + n] : cnt_in[nbase + n];
    rn[n*2 + (tid & 1)] = __builtin_amdgcn_rcpf(fmaxf(c, 1.f));
  }
  __syncthreads();

  // phase 1: stage xc[32][328] bf16, pair-packed b32 writes
  {
    int n = tid >> 2, qq = tid & 3;
    float rci = rn[n*2], rco = rn[n*2 + 1];
    size_t gn = (size_t)(nbase + n);
    if (BF) {
      const short* xr = (const short*)x + gn * 55;
      for (int f = qq; f < 55; f += 4) xc[n*328 + f] = xr[f];
    } else {
      const float* xr = (const float*)x + gn * 55;
      for (int c = qq; c < 27; c += 4) {
        unsigned pk = __builtin_amdgcn_perm(__float_as_uint(xr[2*c+1]), __float_as_uint(xr[2*c]), 0x07060302u);
        *(unsigned*)&xc[n*328 + 2*c] = pk;
      }
      if (qq == 3) xc[n*328 + 54] = (short)(__float_as_uint(xr[54]) >> 16);
    }
    if (qq == 3) { xc[n*328 + 55] = 0; xc[n*328 + 173] = 0; }
    for (int f = 291 + qq; f < 320; f += 4) xc[n*328 + f] = 0;

    const float4* iap = (const float4*)(in_acc  + gn * ROWF);
    const float4* oap = (const float4*)(out_acc + gn * ROWF);
    #pragma unroll
    for (int j4 = 0; j4 < 8; ++j4) {
      int j = qq*32 + j4*4;
      if (j < 116) {
        float4 a = iap[j >> 2];
        float4 b = oap[j >> 2];
        unsigned pi0 = __builtin_amdgcn_perm(__float_as_uint(a.y*rci), __float_as_uint(a.x*rci), 0x07060302u);
        unsigned pi1 = __builtin_amdgcn_perm(__float_as_uint(a.w*rci), __float_as_uint(a.z*rci), 0x07060302u);
        unsigned po0 = __builtin_amdgcn_perm(__float_as_uint(b.y*rco), __float_as_uint(b.x*rco), 0x07060302u);
        unsigned po1 = __builtin_amdgcn_perm(__float_as_uint(b.w*rco), __float_as_uint(b.z*rco), 0x07060302u);
        *(unsigned*)&xc[n*328 + 56 + j]      = pi0;
        *(unsigned*)&xc[n*328 + 56 + j + 2]  = pi1;
        *(unsigned*)&xc[n*328 + 174 + j]     = po0;
        *(unsigned*)&xc[n*328 + 174 + j + 2] = po1;
      }
    }
    if (qq == 3) {   // tail col j=116
      float vi = in_acc [gn * ROWF + 116] * rci;
      float vo = out_acc[gn * ROWF + 116] * rco;
      xc[n*328 + 172] = (short)(__float_as_uint(vi) >> 16);
      xc[n*328 + 290] = (short)(__float_as_uint(vo) >> 16);
    }
  }
  __syncthreads();

  // phase 2: L1 MFMA (acc in regs) + graph column-sums (read-only on xc)
  const short* b1 = (const short*)(ws + OFF_B1);
  f32x4 a1[8];
  #pragma unroll
  for (int T = 0; T < 8; ++T) { float b = p1b[T*16 + nn]; a1[T] = (f32x4){b, b, b, b}; }
  #pragma unroll
  for (int kk = 0; kk < 10; ++kk) {
    short8 af = *(const short8*)&xc[(w*16 + nn) * 328 + kk*32 + q*8];
    #pragma unroll
    for (int T = 0; T < 8; ++T) {
      short8 bfr = *(const short8*)(b1 + ((size_t)(T*10 + kk) * 64 + lane) * 8);
      a1[T] = __builtin_amdgcn_mfma_f32_16x16x32_bf16(af, bfr, a1[T], 0, 0, 0);
    }
  }
  // column sums over 32 nodes, b32-pairified; map xc col -> original feature
  for (int ci = tid; ci < 164; ci += 128) {
    float s0 = 0.f, s1 = 0.f;
    for (int k = 0; k < 32; ++k) {
      unsigned wv = *(const unsigned*)&xc[k*328 + 2*ci];
      s0 += __uint_as_float(wv << 16);
      s1 += __uint_as_float(wv & 0xffff0000u);
    }
    int c0 = 2*ci, c1 = 2*ci + 1;
    if (c0 != 55 && c0 != 173 && c0 < 291) {
      int f = (c0 < 55) ? c0 : (c0 < 173) ? c0 - 1 : c0 - 2;
      sg[f] = s0 * (1.f / 32.f);
    }
    if (c1 != 55 && c1 != 173 && c1 < 291) {
      int f = (c1 < 55) ? c1 : (c1 < 173) ? c1 - 1 : c1 - 2;
      sg[f] = s1 * (1.f / 32.f);
    }
  }
  __syncthreads();

  // phase 3: write h1 (relu, bf16) into xc base, stride 136
  #pragma unroll
  for (int T = 0; T < 8; ++T)
    #pragma unroll
    for (int r = 0; r < 4; ++r)
      xc[(w*16 + q*4 + r) * 136 + T*16 + nn] = (short)f2bf(fmaxf(a1[T][r], 0.f));
  __syncthreads();

  // phase 4: L2 MFMA; h2 to virgin region at short-offset 4608, stride 72
  const short* b2 = (const short*)(ws + OFF_B2);
  f32x4 a2[4];
  #pragma unroll
  for (int T = 0; T < 4; ++T) { float b = p2b[T*16 + nn]; a2[T] = (f32x4){b, b, b, b}; }
  #pragma unroll
  for (int kk = 0; kk < 4; ++kk) {
    short8 af = *(const short8*)&xc[(w*16 + nn) * 136 + kk*32 + q*8];
    #pragma unroll
    for (int T = 0; T < 4; ++T) {
      short8 bfr = *(const short8*)(b2 + ((size_t)(T*4 + kk) * 64 + lane) * 8);
      a2[T] = __builtin_amdgcn_mfma_f32_16x16x32_bf16(af, bfr, a2[T], 0, 0, 0);
    }
  }
  #pragma unroll
  for (int T = 0; T < 4; ++T)
    #pragma unroll
    for (int r = 0; r < 4; ++r)
      xc[4608 + (w*16 + q*4 + r) * 72 + T*16 + nn] = (short)f2bf(fmaxf(a2[T][r], 0.f));
  __syncthreads();

  // phase 5: L3 MFMA + L4 dot + v head
  const short* b3 = (const short*)(ws + OFF_B3);
  f32x4 a3[2];
  #pragma unroll
  for (int T = 0; T < 2; ++T) { float b = p3b[T*16 + nn]; a3[T] = (f32x4){b, b, b, b}; }
  #pragma unroll
  for (int kk = 0; kk < 2; ++kk) {
    short8 af = *(const short8*)&xc[4608 + (w*16 + nn) * 72 + kk*32 + q*8];
    #pragma unroll
    for (int T = 0; T < 2; ++T) {
      short8 bfr = *(const short8*)(b3 + ((size_t)(T*2 + kk) * 64 + lane) * 8);
      a3[T] = __builtin_amdgcn_mfma_f32_16x16x32_bf16(af, bfr, a3[T], 0, 0, 0);
    }
  }
  {
    float w4a = p4w[nn], w4b = p4w[16 + nn];
    float part[4];
    #pragma unroll
    for (int r = 0; r < 4; ++r)
      part[r] = fmaxf(a3[0][r], 0.f) * w4a + fmaxf(a3[1][r], 0.f) * w4b;
    #pragma unroll
    for (int off = 1; off < 16; off <<= 1)
      #pragma unroll
      for (int r = 0; r < 4; ++r) part[r] += __shfl_xor(part[r], off);
    float pv = (nn == 0) ? part[0] : (nn == 1) ? part[1] : (nn == 2) ? part[2] : part[3];
    if (nn < 4) pib[w*16 + q*4 + nn] = pv + p4b0;
  }
  {
    // v head: 128 threads = 32 units x 4 f-chunks
    int u = (tid >> 2) & 31;
    int ch = tid & 3;
    int f0 = ch * 72;
    int f1 = (ch == 3) ? 289 : f0 + 72;
    float r = (ch == 0) ? v1b[u] : 0.f;
    for (int f = f0; f < f1; ++f) r += sg[f] * v1w[f*32 + u];
    r += __shfl_xor(r, 1);
    r += __shfl_xor(r, 2);
    if (ch == 0) vb[u] = fmaxf(r, 0.f) * v2w[u];
  }
  __syncthreads();

  // phase 6: softmax stats + v output (one graph)
  if (tid == 0) {
    float m = -1e30f, s = 0.f, vsum = 0.f;
    for (int k = 0; k < 32; ++k) m = fmaxf(m, pib[k]);
    for (int k = 0; k < 32; ++k) {
      s += __expf(pib[k] - m);
      vsum += vb[k];
    }
    mls[0] = m;
    mls[1] = __logf(s);
    stf<BF>(out, (size_t)NB * ACT + blockIdx.x, vsum + v2b0);
  }
  __syncthreads();

  // phase 7: ragged pack + log_softmax (53 outputs)
  if (tid < 53) {
    float val = (tid < 32) ? pib[tid] : -999.f;
    stf<BF>(out, (size_t)blockIdx.x * 53 + tid, val - mls[0] - mls[1]);
  }
}

__global__ __launch_bounds__(128, 3) void pi_kernel(const int* __restrict__ flag,
                                                    const void* __restrict__ x,
                                                    float* __restrict__ ws,
                                                    void* __restrict__ out)
{
  __shared__ short xc[32 * 328];   // 20992 B; reused as h1 (off 0, stride 136) and h2 (off 4608, stride 72)
  __shared__ float rn[32 * 2];
  __shared__ float sg[296];
  __shared__ float pib[32];
  __shared__ float vb[32];
  __shared__ float mls[2];
  if (*flag) pi_body<true>(xc, rn, sg, pib, vb, mls, x, ws, out);
  else       pi_body<false>(xc, rn, sg, pib, vb, mls, x, ws, out);
}

extern "C" void kernel_launch(void* const* d_in, const int* in_sizes, int n_in,
                              void* d_out, int out_size, void* d_ws, size_t ws_size,
                              hipStream_t stream) {
  const void* x        = d_in[0];
  const void* src_num  = d_in[1];
  const void* tgt_num  = d_in[2];
  const int*  tokens   = (const int*)d_in[3];
  const int*  eidx     = (const int*)d_in[4];
  // d_in[5] = batch: repeat(arange(4096), 32); not needed
  PrepPtrs P;
  P.emb  = d_in[6];
  P.wihf = d_in[7];  P.whhf = d_in[8];  P.bfw = d_in[9];
  P.wihb = d_in[10]; P.whhb = d_in[11]; P.bbw = d_in[12];
  P.p1w = d_in[13]; P.p1b = d_in[14];
  P.p2w = d_in[15]; P.p2b = d_in[16];
  P.p3w = d_in[17]; P.p3b = d_in[18];
  P.p4w = d_in[19]; P.p4b = d_in[20];
  P.v1w = d_in[21]; P.v1b = d_in[22];
  P.v2w = d_in[23]; P.v2b = d_in[24];

  float* ws = (float*)d_ws;
  int* flag = (int*)(ws + OFF_FLAG);

  // zero scatter accumulators + counts (~127 MB)
  hipMemsetAsync(d_ws, 0, ZERO_FLOATS * sizeof(float), stream);

  detect_kernel<<<1, 64, 0, stream>>>((const unsigned int*)x, flag);

  prep_kernel<<<302, 256, 0, stream>>>(flag, P, ws);

  lstm_kernel<<<(NE / 64) * 2, 256, 0, stream>>>(flag, tokens, eidx, src_num, tgt_num, ws);

  pi_kernel<<<NN / 32, 128, 0, stream>>>(flag, x, ws, d_out);
}

// Round 9
// 522.391 us; speedup vs baseline: 1.1194x; 1.1194x over previous
//
#include <hip/hip_runtime.h>
#include <hip/hip_bf16.h>
#include <cstdint>
#include <cstddef>

typedef __hip_bfloat16 bf16;
typedef __attribute__((ext_vector_type(8))) short short8;
typedef __attribute__((ext_vector_type(4))) float f32x4;

#define NE 65536
#define NN 131072
#define TLEN 50
#define NB 4096
#define ACT 53
#define ROWF 120   // padded accumulator row (16B-aligned float4 rows)

// ---------------- workspace layout (float units) ----------------
static constexpr size_t SZ_ACC      = (size_t)NN * ROWF;
static constexpr size_t OFF_IN_ACC  = 0;
static constexpr size_t OFF_OUT_ACC = OFF_IN_ACC + SZ_ACC;
static constexpr size_t OFF_CNT_IN  = OFF_OUT_ACC + SZ_ACC;
static constexpr size_t OFF_CNT_OUT = OFF_CNT_IN + NN;
static constexpr size_t ZERO_FLOATS = OFF_CNT_OUT + NN;          // memset region
// bf16 tables (float-slot units; 2 bf16 per float slot)
static constexpr size_t OFF_ZXF     = ZERO_FLOATS;               // [2][8][64][8] bf16
static constexpr size_t OFF_WFRAG   = OFF_ZXF + 4096;            // [2][8][64][8] bf16 (K-permuted)
static constexpr size_t OFF_B1      = OFF_WFRAG + 4096;          // [8][10][64][8] bf16, k<289 contiguous
static constexpr size_t OFF_B2      = OFF_B1 + 20480;            // [4][4][64][8] bf16
static constexpr size_t OFF_B3      = OFF_B2 + 4096;             // [2][2][64][8] bf16
static constexpr size_t OFF_P1B     = OFF_B3 + 1024;             // fp32
static constexpr size_t OFF_P2B     = OFF_P1B + 128;
static constexpr size_t OFF_P3B     = OFF_P2B + 64;
static constexpr size_t OFF_P4W     = OFF_P3B + 32;
static constexpr size_t OFF_P4B     = OFF_P4W + 32;
static constexpr size_t OFF_V1W     = OFF_P4B + 32;
static constexpr size_t OFF_V1B     = OFF_V1W + 9248;
static constexpr size_t OFF_V2W     = OFF_V1B + 32;
static constexpr size_t OFF_V2B     = OFF_V2W + 32;
static constexpr size_t OFF_FLAG    = OFF_V2B + 32;              // int dtype flag

__device__ __forceinline__ unsigned short f2bf(float f) {      // RNE fp32->bf16 bits
  unsigned u = __float_as_uint(f);
  return (unsigned short)((u + 0x7fffu + ((u >> 16) & 1u)) >> 16);
}
__device__ __forceinline__ float bf2f(short b) {
  return __uint_as_float(((unsigned)(unsigned short)b) << 16);
}
// 3-op sigmoid: t=med3(x,+-4); parabola hits exactly 0/1 at +-4 (no outer clamp).
// max |err| ~= 0.022
__device__ __forceinline__ float sig3(float x) {
  float t = __builtin_amdgcn_fmed3f(x, -4.f, 4.f);
  float p = fmaf(fabsf(t), -0.03125f, 0.25f);
  return fmaf(t, p, 0.5f);
}
// 3-op tanh (= 2*sig3(2x)-1): t=med3(x,+-2); max |err| ~= 0.036
__device__ __forceinline__ float th3(float x) {
  float t = __builtin_amdgcn_fmed3f(x, -2.f, 2.f);
  float p = fmaf(fabsf(t), -0.25f, 1.0f);
  return t * p;
}

template<bool BF>
__device__ __forceinline__ float ldf(const void* p, size_t i) {
  if constexpr (BF) return __bfloat162float(((const bf16*)p)[i]);
  else              return ((const float*)p)[i];
}
template<bool BF>
__device__ __forceinline__ void stf(void* p, size_t i, float v) {
  if constexpr (BF) ((bf16*)p)[i] = __float2bfloat16(v);
  else              ((float*)p)[i] = v;
}

// ---------------- dtype detect: low 16 bits of x words ----------------
__global__ void detect_kernel(const unsigned int* __restrict__ xw, int* __restrict__ flag) {
  int lane = threadIdx.x;
  int cnt = 0;
  #pragma unroll
  for (int i = 0; i < 4; ++i) {
    unsigned w = xw[lane * 4 + i];
    unsigned e = (w >> 7) & 0xFFu;
    cnt += (e >= 100u && e <= 150u) ? 1 : 0;
  }
  #pragma unroll
  for (int off = 32; off; off >>= 1) cnt += __shfl_down(cnt, off);
  if (lane == 0) *flag = (cnt >= 192) ? 1 : 0;   // 1 = bf16 inputs
}

// ---------------- param prep ----------------
struct PrepPtrs {
  const void *emb, *wihf, *whhf, *bfw, *wihb, *whhb, *bbw;
  const void *p1w, *p1b, *p2w, *p2b, *p3w, *p3b, *p4w, *p4b;
  const void *v1w, *v1b, *v2w, *v2b;
};

template<bool BF>
__device__ __forceinline__ void prep_body(int idx, const PrepPtrs P, float* __restrict__ ws) {
  if (idx < 8192) {
    // ZX B-frag: row k = token (0..19, pad 32), col j = T*16+n (gate-major), bias folded
    int d = idx >> 12, r = idx & 4095;
    int T = r >> 9, L = (r >> 3) & 63, jj = r & 7;
    int n = L & 15, q = L >> 4;
    int k = q*8 + jj, col = T*16 + n;
    float s = 0.f;
    if (k < 20) {
      s = ldf<BF>(d ? P.bbw : P.bfw, col);
      const void* wih = d ? P.wihb : P.wihf;
      #pragma unroll
      for (int kk = 0; kk < 8; ++kk)
        s += ldf<BF>(wih, col*8 + kk) * ldf<BF>(P.emb, k*8 + kk);
    }
    ((short*)(ws + OFF_ZXF))[idx] = (short)f2bf(s);
    return;
  }
  idx -= 8192;
  if (idx < 8192) {
    // Whh B-frag, K-PERMUTED: k slot -> original hidden unit u = (k>>1) + 16*(k&1)
    int d = idx >> 12, r = idx & 4095;
    int T = r >> 9, L = (r >> 3) & 63, jj = r & 7;
    int n = L & 15, q = L >> 4;
    int k = q*8 + jj;
    int u = (k >> 1) + 16*(k & 1);
    float v = ldf<BF>(d ? P.whhb : P.whhf, (size_t)(T*16 + n) * 32 + u);
    ((short*)(ws + OFF_WFRAG))[d*4096 + r] = (short)f2bf(v);
    return;
  }
  idx -= 8192;
  if (idx < 40960) {     // p1w B-frags: [NT=8][KT=10][lane][8], zero-pad k>=289
    int r = idx;
    int NTKT = r >> 9, L = (r >> 3) & 63, j = r & 7;
    int NT = NTKT / 10, KT = NTKT - NT * 10;
    int n = L & 15, q = L >> 4;
    int k = KT*32 + q*8 + j, col = NT*16 + n;
    float v = (k < 289) ? ldf<BF>(P.p1w, (size_t)k * 128 + col) : 0.f;
    ((short*)(ws + OFF_B1))[r] = (short)f2bf(v);
    return;
  }
  idx -= 40960;
  if (idx < 8192) {      // p2w B-frags: [NT=4][KT=4][lane][8]
    int r = idx;
    int NTKT = r >> 9, L = (r >> 3) & 63, j = r & 7;
    int NT = NTKT >> 2, KT = NTKT & 3;
    int n = L & 15, q = L >> 4;
    int k = KT*32 + q*8 + j, col = NT*16 + n;
    ((short*)(ws + OFF_B2))[r] = (short)f2bf(ldf<BF>(P.p2w, (size_t)k * 64 + col));
    return;
  }
  idx -= 8192;
  if (idx < 2048) {      // p3w B-frags: [NT=2][KT=2][lane][8]
    int r = idx;
    int NTKT = r >> 9, L = (r >> 3) & 63, j = r & 7;
    int NT = NTKT >> 1, KT = NTKT & 1;
    int n = L & 15, q = L >> 4;
    int k = KT*32 + q*8 + j, col = NT*16 + n;
    ((short*)(ws + OFF_B3))[r] = (short)f2bf(ldf<BF>(P.p3w, (size_t)k * 32 + col));
    return;
  }
  idx -= 2048;
  #define CPY(src, off, n) if (idx < (n)) { ws[(off) + idx] = ldf<BF>(src, idx); return; } idx -= (n);
  CPY(P.p1b, OFF_P1B, 128)
  CPY(P.p2b, OFF_P2B, 64)
  CPY(P.p3b, OFF_P3B, 32)
  CPY(P.p4w, OFF_P4W, 32)
  CPY(P.p4b, OFF_P4B, 1)
  CPY(P.v1w, OFF_V1W, 9248)
  CPY(P.v1b, OFF_V1B, 32)
  CPY(P.v2w, OFF_V2W, 32)
  CPY(P.v2b, OFF_V2B, 1)
  #undef CPY
}

__global__ void prep_kernel(const int* __restrict__ flag, const PrepPtrs P, float* __restrict__ ws) {
  int idx = blockIdx.x * 256 + threadIdx.x;
  if (*flag) prep_body<true>(idx, P, ws);
  else       prep_body<false>(idx, P, ws);
}

// ---------------- bi-LSTM via MFMA + scatter-mean accumulate ----------------
// Direction-split blocks; 3-op med3/fma gate nonlinearities (no exp/rcp).
// z = onehot(tok)@ZX + H@Whh^T (16 MFMAs/step).
template<bool BF>
__device__ __forceinline__ void lstm_body(
    short (*tk_s)[800], short (*h_s)[640],
    const int* __restrict__ tokens, const int* __restrict__ eidx,
    const void* __restrict__ src_num, const void* __restrict__ tgt_num,
    float* __restrict__ ws)
{
  float* in_acc  = ws + OFF_IN_ACC;
  float* out_acc = ws + OFF_OUT_ACC;
  float* cnt_in  = ws + OFF_CNT_IN;
  float* cnt_out = ws + OFF_CNT_OUT;
  const short* wfp = (const short*)(ws + OFF_WFRAG);
  const short* zxp = (const short*)(ws + OFF_ZXF);

  const int tid  = threadIdx.x;
  const int w    = tid >> 6;
  const int lane = tid & 63;
  const int n    = lane & 15;
  const int quad = lane >> 4;
  const int d    = blockIdx.x & 1;
  const int ebase = (blockIdx.x >> 1) * 64 + w * 16;

  for (int i = lane; i < 16 * TLEN; i += 64) {
    int e = i / TLEN, t = i - e * TLEN;
    tk_s[w][t * 16 + e] = (short)tokens[(size_t)(ebase + e) * TLEN + t];
  }
  __syncthreads();

  short8 wfr[8], zxfr[8];
  #pragma unroll
  for (int T = 0; T < 8; ++T) {
    wfr[T]  = *(const short8*)(wfp + d*4096 + T*512 + lane*8);
    zxfr[T] = *(const short8*)(zxp + d*4096 + T*512 + lane*8);
  }
  for (int i = lane; i < 320; i += 64) ((int*)h_s[w])[i] = 0;

  float c_[2][4], accm[2][4];
  #pragma unroll
  for (int p = 0; p < 2; ++p)
    #pragma unroll
    for (int r = 0; r < 4; ++r) { c_[p][r] = 0.f; accm[p][r] = 0.f; }

  const f32x4 zeroC = {0.f, 0.f, 0.f, 0.f};

  for (int t = 0; t < TLEN; ++t) {
    const int tt = d ? (TLEN - 1 - t) : t;
    const int tok = (int)tk_s[w][tt * 16 + n];

    int4 dwv;
    {
      int k0 = quad * 8;
      int v0 = (tok == k0    ) ? 0x3F80 : 0; v0 = (tok == k0 + 1) ? 0x3F800000 : v0;
      int v1 = (tok == k0 + 2) ? 0x3F80 : 0; v1 = (tok == k0 + 3) ? 0x3F800000 : v1;
      int v2 = (tok == k0 + 4) ? 0x3F80 : 0; v2 = (tok == k0 + 5) ? 0x3F800000 : v2;
      int v3 = (tok == k0 + 6) ? 0x3F80 : 0; v3 = (tok == k0 + 7) ? 0x3F800000 : v3;
      dwv = (int4){v0, v1, v2, v3};
    }
    short8 af2 = *reinterpret_cast<short8*>(&dwv);
    short8 af = *(const short8*)&h_s[w][n * 40 + quad * 8];

    f32x4 acc4[8];
    #pragma unroll
    for (int T = 0; T < 8; ++T)
      acc4[T] = __builtin_amdgcn_mfma_f32_16x16x32_bf16(af2, zxfr[T], zeroC, 0, 0, 0);
    #pragma unroll
    for (int T = 0; T < 8; ++T)
      acc4[T] = __builtin_amdgcn_mfma_f32_16x16x32_bf16(af, wfr[T], acc4[T], 0, 0, 0);

    // gates: tiles 0,1=i  2,3=f  4,5=g  6,7=o (p = tile&1)
    #pragma unroll
    for (int r = 0; r < 4; ++r) {
      float hvp[2];
      #pragma unroll
      for (int p = 0; p < 2; ++p) {
        float si = sig3(acc4[p][r]);
        float sf = sig3(acc4[2+p][r]);
        float tg = th3 (acc4[4+p][r]);
        float so = sig3(acc4[6+p][r]);
        float cv = fmaf(sf, c_[p][r], si * tg);
        c_[p][r] = cv;
        float hv = so * th3(cv);
        accm[p][r] += hv;
        hvp[p] = hv;
      }
      unsigned pk = __builtin_amdgcn_perm(__float_as_uint(hvp[1]), __float_as_uint(hvp[0]), 0x07060302u);
      *(unsigned*)&h_s[w][(quad*4 + r) * 40 + 2*n] = pk;
    }
  }

  // scatter this direction's mean into feature slots [53+32d, 85+32d)
  const int fb = 53 + 32 * d;
  #pragma unroll
  for (int r = 0; r < 4; ++r) {
    int e  = ebase + quad * 4 + r;
    size_t so = (size_t)eidx[e] * ROWF;
    size_t to = (size_t)eidx[NE + e] * ROWF;
    float m0 = accm[0][r] * 0.02f;
    float m1 = accm[1][r] * 0.02f;
    atomicAdd(out_acc + so + fb + n,      m0);
    atomicAdd(out_acc + so + fb + n + 16, m1);
    atomicAdd(in_acc  + to + fb + n,      m0);
    atomicAdd(in_acc  + to + fb + n + 16, m1);
  }
  if (d == 0) {
    for (int i = lane; i < 16 * 53; i += 64) {
      int e = i / 53, f = i - e * 53;
      int ge = ebase + e;
      atomicAdd(out_acc + (size_t)eidx[ge] * ROWF + f,      ldf<BF>(tgt_num, (size_t)ge * 53 + f));
      atomicAdd(in_acc  + (size_t)eidx[NE + ge] * ROWF + f, ldf<BF>(src_num, (size_t)ge * 53 + f));
    }
    if (lane < 16) {
      int ge = ebase + lane;
      atomicAdd(cnt_out + eidx[ge], 1.f);
      atomicAdd(cnt_in  + eidx[NE + ge], 1.f);
    }
  }
}

__global__ __launch_bounds__(256) void lstm_kernel(
    const int* __restrict__ flag,
    const int* __restrict__ tokens, const int* __restrict__ eidx,
    const void* __restrict__ src_num, const void* __restrict__ tgt_num,
    float* __restrict__ ws)
{
  __shared__ short tk_s[4][800];
  __shared__ short h_s[4][640];
  if (*flag) lstm_body<true>(tk_s, h_s, tokens, eidx, src_num, tgt_num, ws);
  else       lstm_body<false>(tk_s, h_s, tokens, eidx, src_num, tgt_num, ws);
}

// ---------------- fused node-MLP (MFMA) + graph pool + v head + log_softmax ----------------
// Block = 256 threads (4 waves) = 64 nodes = exactly 2 graphs.  (r7 shape — best measured)
template<bool BF>
__device__ __forceinline__ void pi_body(
    short* __restrict__ xc, float* __restrict__ rn, float* __restrict__ sg,
    float* __restrict__ pib, float* __restrict__ vb, float* __restrict__ mls,
    const void* __restrict__ x, float* __restrict__ ws, void* __restrict__ out)
{
  const float* in_acc  = ws + OFF_IN_ACC;
  const float* out_acc = ws + OFF_OUT_ACC;
  const float* cnt_in  = ws + OFF_CNT_IN;
  const float* cnt_out = ws + OFF_CNT_OUT;
  const float* p1b = ws + OFF_P1B;
  const float* p2b = ws + OFF_P2B;
  const float* p3b = ws + OFF_P3B;
  const float* p4w = ws + OFF_P4W;
  const float* v1w = ws + OFF_V1W;
  const float* v1b = ws + OFF_V1B;
  const float* v2w = ws + OFF_V2W;
  const float p4b0 = ws[OFF_P4B];
  const float v2b0 = ws[OFF_V2B];

  const int tid = threadIdx.x;
  const int w = tid >> 6, lane = tid & 63;
  const int nn = lane & 15, q = lane >> 4;
  const int nbase = blockIdx.x * 64;

  // phase 0: per-node reciprocals
  if (tid < 128) {
    int n = tid >> 1;
    float c = (tid & 1) ? cnt_out[nbase + n] : cnt_in[nbase + n];
    rn[n*2 + (tid & 1)] = __builtin_amdgcn_rcpf(fmaxf(c, 1.f));
  }
  __syncthreads();

  // phase 1: stage xc[64][328] bf16 via float4 loads (acc rows padded to 120)
  {
    int n = tid >> 2, qq = tid & 3;
    float rci = rn[n*2], rco = rn[n*2 + 1];
    for (int f = qq; f < 55; f += 4)
      xc[n*328 + f] = (short)f2bf(ldf<BF>(x, (size_t)(nbase + n) * 55 + f));
    const float4* iap = (const float4*)(in_acc  + (size_t)(nbase + n) * ROWF);
    const float4* oap = (const float4*)(out_acc + (size_t)(nbase + n) * ROWF);
    #pragma unroll
    for (int j4 = 0; j4 < 8; ++j4) {
      int j = qq*32 + j4*4;
      if (j < 117) {
        float4 v  = iap[j >> 2];
        float4 u2 = oap[j >> 2];
        xc[n*328 + 55 + j]  = (short)f2bf(v.x * rci);
        xc[n*328 + 172 + j] = (short)f2bf(u2.x * rco);
        if (j + 1 < 117) { xc[n*328 + 56 + j]  = (short)f2bf(v.y * rci);
                           xc[n*328 + 173 + j] = (short)f2bf(u2.y * rco); }
        if (j + 2 < 117) { xc[n*328 + 57 + j]  = (short)f2bf(v.z * rci);
                           xc[n*328 + 174 + j] = (short)f2bf(u2.z * rco); }
        if (j + 3 < 117) { xc[n*328 + 58 + j]  = (short)f2bf(v.w * rci);
                           xc[n*328 + 175 + j] = (short)f2bf(u2.w * rco); }
      }
    }
    for (int f = 289 + qq; f < 320; f += 4) xc[n*328 + f] = 0;
  }
  __syncthreads();

  // phase 2: L1 MFMA (acc in regs) + graph column-sums (both read-only on xc)
  const short* b1 = (const short*)(ws + OFF_B1);
  f32x4 a1[8];
  #pragma unroll
  for (int T = 0; T < 8; ++T) { float b = p1b[T*16 + nn]; a1[T] = (f32x4){b, b, b, b}; }
  #pragma unroll
  for (int kk = 0; kk < 10; ++kk) {
    short8 af = *(const short8*)&xc[(w*16 + nn) * 328 + kk*32 + q*8];
    #pragma unroll
    for (int T = 0; T < 8; ++T) {
      short8 bfr = *(const short8*)(b1 + ((size_t)(T*10 + kk) * 64 + lane) * 8);
      a1[T] = __builtin_amdgcn_mfma_f32_16x16x32_bf16(af, bfr, a1[T], 0, 0, 0);
    }
  }
  for (int i = tid; i < 578; i += 256) {
    int g = (i >= 289) ? 1 : 0;
    int f = i - g * 289;
    float s = 0.f;
    for (int k = 0; k < 32; ++k) s += bf2f(xc[(g*32 + k) * 328 + f]);
    sg[g*296 + f] = s * (1.f / 32.f);
  }
  __syncthreads();

  // phase 3: write h1 (relu, bf16) into xc base region, stride 136
  #pragma unroll
  for (int T = 0; T < 8; ++T)
    #pragma unroll
    for (int r = 0; r < 4; ++r)
      xc[(w*16 + q*4 + r) * 136 + T*16 + nn] = (short)f2bf(fmaxf(a1[T][r], 0.f));
  __syncthreads();

  // phase 4: L2 MFMA; h2 to virgin region at short-offset 8704, stride 72
  const short* b2 = (const short*)(ws + OFF_B2);
  f32x4 a2[4];
  #pragma unroll
  for (int T = 0; T < 4; ++T) { float b = p2b[T*16 + nn]; a2[T] = (f32x4){b, b, b, b}; }
  #pragma unroll
  for (int kk = 0; kk < 4; ++kk) {
    short8 af = *(const short8*)&xc[(w*16 + nn) * 136 + kk*32 + q*8];
    #pragma unroll
    for (int T = 0; T < 4; ++T) {
      short8 bfr = *(const short8*)(b2 + ((size_t)(T*4 + kk) * 64 + lane) * 8);
      a2[T] = __builtin_amdgcn_mfma_f32_16x16x32_bf16(af, bfr, a2[T], 0, 0, 0);
    }
  }
  #pragma unroll
  for (int T = 0; T < 4; ++T)
    #pragma unroll
    for (int r = 0; r < 4; ++r)
      xc[8704 + (w*16 + q*4 + r) * 72 + T*16 + nn] = (short)f2bf(fmaxf(a2[T][r], 0.f));
  __syncthreads();

  // phase 5: L3 MFMA + L4 dot + v head
  const short* b3 = (const short*)(ws + OFF_B3);
  f32x4 a3[2];
  #pragma unroll
  for (int T = 0; T < 2; ++T) { float b = p3b[T*16 + nn]; a3[T] = (f32x4){b, b, b, b}; }
  #pragma unroll
  for (int kk = 0; kk < 2; ++kk) {
    short8 af = *(const short8*)&xc[8704 + (w*16 + nn) * 72 + kk*32 + q*8];
    #pragma unroll
    for (int T = 0; T < 2; ++T) {
      short8 bfr = *(const short8*)(b3 + ((size_t)(T*2 + kk) * 64 + lane) * 8);
      a3[T] = __builtin_amdgcn_mfma_f32_16x16x32_bf16(af, bfr, a3[T], 0, 0, 0);
    }
  }
  {
    float w4a = p4w[nn], w4b = p4w[16 + nn];
    float part[4];
    #pragma unroll
    for (int r = 0; r < 4; ++r)
      part[r] = fmaxf(a3[0][r], 0.f) * w4a + fmaxf(a3[1][r], 0.f) * w4b;
    #pragma unroll
    for (int off = 1; off < 16; off <<= 1)
      #pragma unroll
      for (int r = 0; r < 4; ++r) part[r] += __shfl_xor(part[r], off);
    float pv = (nn == 0) ? part[0] : (nn == 1) ? part[1] : (nn == 2) ? part[2] : part[3];
    if (nn < 4) pib[w*16 + q*4 + nn] = pv + p4b0;
  }
  {
    // v head: 256 threads = 2 graphs x 32 units x 4 f-chunks
    int g = tid >> 7;
    int u = (tid >> 2) & 31;
    int ch = tid & 3;
    int f0 = ch * 72;
    int f1 = (ch == 3) ? 289 : f0 + 72;
    float r = (ch == 0) ? v1b[u] : 0.f;
    for (int f = f0; f < f1; ++f) r += sg[g*296 + f] * v1w[f*32 + u];
    r += __shfl_xor(r, 1);
    r += __shfl_xor(r, 2);
    if (ch == 0) vb[g*32 + u] = fmaxf(r, 0.f) * v2w[u];
  }
  __syncthreads();

  // phase 6: per-graph softmax stats + v output
  if (tid < 2) {
    float m = -1e30f, s = 0.f, vsum = 0.f;
    for (int k = 0; k < 32; ++k) m = fmaxf(m, pib[tid*32 + k]);
    for (int k = 0; k < 32; ++k) {
      s += __expf(pib[tid*32 + k] - m);
      vsum += vb[tid*32 + k];
    }
    mls[tid*2] = m;
    mls[tid*2 + 1] = __logf(s);
    stf<BF>(out, (size_t)NB * ACT + 2*blockIdx.x + tid, vsum + v2b0);
  }
  __syncthreads();

  // phase 7: ragged pack + log_softmax (106 outputs)
  if (tid < 106) {
    int g = (tid >= 53) ? 1 : 0;
    int c = tid - g * 53;
    float val = (c < 32) ? pib[g*32 + c] : -999.f;
    stf<BF>(out, (size_t)(2*blockIdx.x + g) * 53 + c, val - mls[g*2] - mls[g*2 + 1]);
  }
}

__global__ __launch_bounds__(256, 3) void pi_kernel(const int* __restrict__ flag,
                                                    const void* __restrict__ x,
                                                    float* __restrict__ ws,
                                                    void* __restrict__ out)
{
  __shared__ short xc[64 * 328];   // 41984 B; reused as h1 (off 0, stride 136) and h2 (off 8704, stride 72)
  __shared__ float rn[64 * 2];
  __shared__ float sg[2 * 296];
  __shared__ float pib[64];
  __shared__ float vb[64];
  __shared__ float mls[4];
  if (*flag) pi_body<true>(xc, rn, sg, pib, vb, mls, x, ws, out);
  else       pi_body<false>(xc, rn, sg, pib, vb, mls, x, ws, out);
}

extern "C" void kernel_launch(void* const* d_in, const int* in_sizes, int n_in,
                              void* d_out, int out_size, void* d_ws, size_t ws_size,
                              hipStream_t stream) {
  const void* x        = d_in[0];
  const void* src_num  = d_in[1];
  const void* tgt_num  = d_in[2];
  const int*  tokens   = (const int*)d_in[3];
  const int*  eidx     = (const int*)d_in[4];
  // d_in[5] = batch: repeat(arange(4096), 32); not needed
  PrepPtrs P;
  P.emb  = d_in[6];
  P.wihf = d_in[7];  P.whhf = d_in[8];  P.bfw = d_in[9];
  P.wihb = d_in[10]; P.whhb = d_in[11]; P.bbw = d_in[12];
  P.p1w = d_in[13]; P.p1b = d_in[14];
  P.p2w = d_in[15]; P.p2b = d_in[16];
  P.p3w = d_in[17]; P.p3b = d_in[18];
  P.p4w = d_in[19]; P.p4b = d_in[20];
  P.v1w = d_in[21]; P.v1b = d_in[22];
  P.v2w = d_in[23]; P.v2b = d_in[24];

  float* ws = (float*)d_ws;
  int* flag = (int*)(ws + OFF_FLAG);

  // zero scatter accumulators + counts (~127 MB)
  hipMemsetAsync(d_ws, 0, ZERO_FLOATS * sizeof(float), stream);

  detect_kernel<<<1, 64, 0, stream>>>((const unsigned int*)x, flag);

  prep_kernel<<<302, 256, 0, stream>>>(flag, P, ws);

  lstm_kernel<<<(NE / 64) * 2, 256, 0, stream>>>(flag, tokens, eidx, src_num, tgt_num, ws);

  pi_kernel<<<NN / 64, 256, 0, stream>>>(flag, x, ws, d_out);
}

// Round 10
// 487.623 us; speedup vs baseline: 1.1992x; 1.0713x over previous
//
#include <hip/hip_runtime.h>
#include <hip/hip_bf16.h>
#include <cstdint>
#include <cstddef>

typedef __hip_bfloat16 bf16;
typedef __attribute__((ext_vector_type(8))) short short8;
typedef __attribute__((ext_vector_type(4))) float f32x4;

#define NE 65536
#define NN 131072
#define TLEN 50
#define NB 4096
#define ACT 53
#define ROWF 120   // padded accumulator row (16B-aligned float4 rows)

// ---------------- workspace layout (float units) ----------------
static constexpr size_t SZ_ACC      = (size_t)NN * ROWF;
static constexpr size_t OFF_IN_ACC  = 0;
static constexpr size_t OFF_OUT_ACC = OFF_IN_ACC + SZ_ACC;
static constexpr size_t OFF_CNT_IN  = OFF_OUT_ACC + SZ_ACC;
static constexpr size_t OFF_CNT_OUT = OFF_CNT_IN + NN;
static constexpr size_t ZERO_FLOATS = OFF_CNT_OUT + NN;          // memset region
// bf16 tables (float-slot units; 2 bf16 per float slot)
static constexpr size_t OFF_ZXF     = ZERO_FLOATS;               // [2][8][64][8] bf16
static constexpr size_t OFF_WFRAG   = OFF_ZXF + 4096;            // [2][8][64][8] bf16 (K-permuted)
static constexpr size_t OFF_B1      = OFF_WFRAG + 4096;          // [8][10][64][8] bf16, k<289 contiguous
static constexpr size_t OFF_B2      = OFF_B1 + 20480;            // [4][4][64][8] bf16
static constexpr size_t OFF_B3      = OFF_B2 + 4096;             // [2][2][64][8] bf16
static constexpr size_t OFF_P1B     = OFF_B3 + 1024;             // fp32
static constexpr size_t OFF_P2B     = OFF_P1B + 128;
static constexpr size_t OFF_P3B     = OFF_P2B + 64;
static constexpr size_t OFF_P4W     = OFF_P3B + 32;
static constexpr size_t OFF_P4B     = OFF_P4W + 32;
static constexpr size_t OFF_V1W     = OFF_P4B + 32;
static constexpr size_t OFF_V1B     = OFF_V1W + 9248;
static constexpr size_t OFF_V2W     = OFF_V1B + 32;
static constexpr size_t OFF_V2B     = OFF_V2W + 32;
static constexpr size_t OFF_FLAG    = OFF_V2B + 32;              // int dtype flag

__device__ __forceinline__ unsigned short f2bf(float f) {      // RNE fp32->bf16 bits
  unsigned u = __float_as_uint(f);
  return (unsigned short)((u + 0x7fffu + ((u >> 16) & 1u)) >> 16);
}
__device__ __forceinline__ float bf2f(short b) {
  return __uint_as_float(((unsigned)(unsigned short)b) << 16);
}
// 3-op sigmoid: t=med3(x,+-4); parabola hits exactly 0/1 at +-4. max |err| ~= 0.022
__device__ __forceinline__ float sig3(float x) {
  float t = __builtin_amdgcn_fmed3f(x, -4.f, 4.f);
  float p = fmaf(fabsf(t), -0.03125f, 0.25f);
  return fmaf(t, p, 0.5f);
}
// 3-op tanh (= 2*sig3(2x)-1): t=med3(x,+-2); max |err| ~= 0.036
__device__ __forceinline__ float th3(float x) {
  float t = __builtin_amdgcn_fmed3f(x, -2.f, 2.f);
  float p = fmaf(fabsf(t), -0.25f, 1.0f);
  return t * p;
}

template<bool BF>
__device__ __forceinline__ float ldf(const void* p, size_t i) {
  if constexpr (BF) return __bfloat162float(((const bf16*)p)[i]);
  else              return ((const float*)p)[i];
}
template<bool BF>
__device__ __forceinline__ void stf(void* p, size_t i, float v) {
  if constexpr (BF) ((bf16*)p)[i] = __float2bfloat16(v);
  else              ((float*)p)[i] = v;
}

// ---------------- dtype detect: low 16 bits of x words ----------------
__global__ void detect_kernel(const unsigned int* __restrict__ xw, int* __restrict__ flag) {
  int lane = threadIdx.x;
  int cnt = 0;
  #pragma unroll
  for (int i = 0; i < 4; ++i) {
    unsigned w = xw[lane * 4 + i];
    unsigned e = (w >> 7) & 0xFFu;
    cnt += (e >= 100u && e <= 150u) ? 1 : 0;
  }
  #pragma unroll
  for (int off = 32; off; off >>= 1) cnt += __shfl_down(cnt, off);
  if (lane == 0) *flag = (cnt >= 192) ? 1 : 0;   // 1 = bf16 inputs
}

// ---------------- param prep ----------------
struct PrepPtrs {
  const void *emb, *wihf, *whhf, *bfw, *wihb, *whhb, *bbw;
  const void *p1w, *p1b, *p2w, *p2b, *p3w, *p3b, *p4w, *p4b;
  const void *v1w, *v1b, *v2w, *v2b;
};

template<bool BF>
__device__ __forceinline__ void prep_body(int idx, const PrepPtrs P, float* __restrict__ ws) {
  if (idx < 8192) {
    // ZX B-frag: row k = token (0..19, pad 32), col j = T*16+n (gate-major), bias folded
    int d = idx >> 12, r = idx & 4095;
    int T = r >> 9, L = (r >> 3) & 63, jj = r & 7;
    int n = L & 15, q = L >> 4;
    int k = q*8 + jj, col = T*16 + n;
    float s = 0.f;
    if (k < 20) {
      s = ldf<BF>(d ? P.bbw : P.bfw, col);
      const void* wih = d ? P.wihb : P.wihf;
      #pragma unroll
      for (int kk = 0; kk < 8; ++kk)
        s += ldf<BF>(wih, col*8 + kk) * ldf<BF>(P.emb, k*8 + kk);
    }
    ((short*)(ws + OFF_ZXF))[idx] = (short)f2bf(s);
    return;
  }
  idx -= 8192;
  if (idx < 8192) {
    // Whh B-frag, K-PERMUTED: k slot -> original hidden unit u = (k>>1) + 16*(k&1)
    int d = idx >> 12, r = idx & 4095;
    int T = r >> 9, L = (r >> 3) & 63, jj = r & 7;
    int n = L & 15, q = L >> 4;
    int k = q*8 + jj;
    int u = (k >> 1) + 16*(k & 1);
    float v = ldf<BF>(d ? P.whhb : P.whhf, (size_t)(T*16 + n) * 32 + u);
    ((short*)(ws + OFF_WFRAG))[d*4096 + r] = (short)f2bf(v);
    return;
  }
  idx -= 8192;
  if (idx < 40960) {     // p1w B-frags: [NT=8][KT=10][lane][8], zero-pad k>=289
    int r = idx;
    int NTKT = r >> 9, L = (r >> 3) & 63, j = r & 7;
    int NT = NTKT / 10, KT = NTKT - NT * 10;
    int n = L & 15, q = L >> 4;
    int k = KT*32 + q*8 + j, col = NT*16 + n;
    float v = (k < 289) ? ldf<BF>(P.p1w, (size_t)k * 128 + col) : 0.f;
    ((short*)(ws + OFF_B1))[r] = (short)f2bf(v);
    return;
  }
  idx -= 40960;
  if (idx < 8192) {      // p2w B-frags: [NT=4][KT=4][lane][8]
    int r = idx;
    int NTKT = r >> 9, L = (r >> 3) & 63, j = r & 7;
    int NT = NTKT >> 2, KT = NTKT & 3;
    int n = L & 15, q = L >> 4;
    int k = KT*32 + q*8 + j, col = NT*16 + n;
    ((short*)(ws + OFF_B2))[r] = (short)f2bf(ldf<BF>(P.p2w, (size_t)k * 64 + col));
    return;
  }
  idx -= 8192;
  if (idx < 2048) {      // p3w B-frags: [NT=2][KT=2][lane][8]
    int r = idx;
    int NTKT = r >> 9, L = (r >> 3) & 63, j = r & 7;
    int NT = NTKT >> 1, KT = NTKT & 1;
    int n = L & 15, q = L >> 4;
    int k = KT*32 + q*8 + j, col = NT*16 + n;
    ((short*)(ws + OFF_B3))[r] = (short)f2bf(ldf<BF>(P.p3w, (size_t)k * 32 + col));
    return;
  }
  idx -= 2048;
  #define CPY(src, off, n) if (idx < (n)) { ws[(off) + idx] = ldf<BF>(src, idx); return; } idx -= (n);
  CPY(P.p1b, OFF_P1B, 128)
  CPY(P.p2b, OFF_P2B, 64)
  CPY(P.p3b, OFF_P3B, 32)
  CPY(P.p4w, OFF_P4W, 32)
  CPY(P.p4b, OFF_P4B, 1)
  CPY(P.v1w, OFF_V1W, 9248)
  CPY(P.v1b, OFF_V1B, 32)
  CPY(P.v2w, OFF_V2W, 32)
  CPY(P.v2b, OFF_V2B, 1)
  #undef CPY
}

__global__ void prep_kernel(const int* __restrict__ flag, const PrepPtrs P, float* __restrict__ ws) {
  int idx = blockIdx.x * 256 + threadIdx.x;
  if (*flag) prep_body<true>(idx, P, ws);
  else       prep_body<false>(idx, P, ws);
}

// ---------------- bi-LSTM via MFMA + scatter-mean accumulate ----------------
// 128-thread blocks (2 waves x 16 edges), direction-split grid (4096 blocks).
// Shift-built one-hot A-frag; 3-op med3/fma gate nonlinearities.
template<bool BF>
__device__ __forceinline__ void lstm_body(
    short (*tk_s)[800], short (*h_s)[640],
    const int* __restrict__ tokens, const int* __restrict__ eidx,
    const void* __restrict__ src_num, const void* __restrict__ tgt_num,
    float* __restrict__ ws)
{
  float* in_acc  = ws + OFF_IN_ACC;
  float* out_acc = ws + OFF_OUT_ACC;
  float* cnt_in  = ws + OFF_CNT_IN;
  float* cnt_out = ws + OFF_CNT_OUT;
  const short* wfp = (const short*)(ws + OFF_WFRAG);
  const short* zxp = (const short*)(ws + OFF_ZXF);

  const int tid  = threadIdx.x;
  const int w    = tid >> 6;
  const int lane = tid & 63;
  const int n    = lane & 15;
  const int quad = lane >> 4;
  const int d    = blockIdx.x & 1;
  const int ebase = (blockIdx.x >> 1) * 32 + w * 16;

  // stage this wave's tokens transposed (wave-private; no barrier needed)
  for (int i = lane; i < 16 * TLEN; i += 64) {
    int e = i / TLEN, t = i - e * TLEN;
    tk_s[w][t * 16 + e] = (short)tokens[(size_t)(ebase + e) * TLEN + t];
  }

  short8 wfr[8], zxfr[8];
  #pragma unroll
  for (int T = 0; T < 8; ++T) {
    wfr[T]  = *(const short8*)(wfp + d*4096 + T*512 + lane*8);
    zxfr[T] = *(const short8*)(zxp + d*4096 + T*512 + lane*8);
  }
  for (int i = lane; i < 320; i += 64) ((int*)h_s[w])[i] = 0;

  float c_[2][4], accm[2][4];
  #pragma unroll
  for (int p = 0; p < 2; ++p)
    #pragma unroll
    for (int r = 0; r < 4; ++r) { c_[p][r] = 0.f; accm[p][r] = 0.f; }

  const f32x4 zeroC = {0.f, 0.f, 0.f, 0.f};

  for (int t = 0; t < TLEN; ++t) {
    const int tt = d ? (TLEN - 1 - t) : t;
    const int tok = (int)tk_s[w][tt * 16 + n];

    // one-hot A-frag via shared 64-bit shift: slot kk = tok - quad*8 gets bf16 1.0
    int kk = tok - (quad << 3);
    unsigned a = ((unsigned)kk & 3u) << 4;
    unsigned long long sh = 0x3F80ULL << a;
    unsigned long long oh[2];
    oh[0] = ((unsigned)kk < 4u) ? sh : 0ULL;
    oh[1] = ((unsigned)(kk - 4) < 4u) ? sh : 0ULL;
    short8 af2 = *reinterpret_cast<short8*>(oh);
    short8 af = *(const short8*)&h_s[w][n * 40 + quad * 8];   // K-permuted cols

    f32x4 acc4[8];
    #pragma unroll
    for (int T = 0; T < 8; ++T)
      acc4[T] = __builtin_amdgcn_mfma_f32_16x16x32_bf16(af2, zxfr[T], zeroC, 0, 0, 0);
    #pragma unroll
    for (int T = 0; T < 8; ++T)
      acc4[T] = __builtin_amdgcn_mfma_f32_16x16x32_bf16(af, wfr[T], acc4[T], 0, 0, 0);

    // gates: tiles 0,1=i  2,3=f  4,5=g  6,7=o (p = tile&1)
    #pragma unroll
    for (int r = 0; r < 4; ++r) {
      float hvp[2];
      #pragma unroll
      for (int p = 0; p < 2; ++p) {
        float si = sig3(acc4[p][r]);
        float sf = sig3(acc4[2+p][r]);
        float tg = th3 (acc4[4+p][r]);
        float so = sig3(acc4[6+p][r]);
        float cv = fmaf(sf, c_[p][r], si * tg);
        c_[p][r] = cv;
        float hv = so * th3(cv);
        accm[p][r] += hv;
        hvp[p] = hv;
      }
      unsigned pk = __builtin_amdgcn_perm(__float_as_uint(hvp[1]), __float_as_uint(hvp[0]), 0x07060302u);
      *(unsigned*)&h_s[w][(quad*4 + r) * 40 + 2*n] = pk;
    }
  }

  // scatter this direction's mean into feature slots [53+32d, 85+32d)
  const int fb = 53 + 32 * d;
  #pragma unroll
  for (int r = 0; r < 4; ++r) {
    int e  = ebase + quad * 4 + r;
    size_t so = (size_t)eidx[e] * ROWF;
    size_t to = (size_t)eidx[NE + e] * ROWF;
    float m0 = accm[0][r] * 0.02f;
    float m1 = accm[1][r] * 0.02f;
    atomicAdd(out_acc + so + fb + n,      m0);
    atomicAdd(out_acc + so + fb + n + 16, m1);
    atomicAdd(in_acc  + to + fb + n,      m0);
    atomicAdd(in_acc  + to + fb + n + 16, m1);
  }
  if (d == 0) {
    for (int i = lane; i < 16 * 53; i += 64) {
      int e = i / 53, f = i - e * 53;
      int ge = ebase + e;
      atomicAdd(out_acc + (size_t)eidx[ge] * ROWF + f,      ldf<BF>(tgt_num, (size_t)ge * 53 + f));
      atomicAdd(in_acc  + (size_t)eidx[NE + ge] * ROWF + f, ldf<BF>(src_num, (size_t)ge * 53 + f));
    }
    if (lane < 16) {
      int ge = ebase + lane;
      atomicAdd(cnt_out + eidx[ge], 1.f);
      atomicAdd(cnt_in  + eidx[NE + ge], 1.f);
    }
  }
}

__global__ __launch_bounds__(128) void lstm_kernel(
    const int* __restrict__ flag,
    const int* __restrict__ tokens, const int* __restrict__ eidx,
    const void* __restrict__ src_num, const void* __restrict__ tgt_num,
    float* __restrict__ ws)
{
  __shared__ short tk_s[2][800];
  __shared__ short h_s[2][640];
  if (*flag) lstm_body<true>(tk_s, h_s, tokens, eidx, src_num, tgt_num, ws);
  else       lstm_body<false>(tk_s, h_s, tokens, eidx, src_num, tgt_num, ws);
}

// ---------------- fused node-MLP (MFMA) + graph pool + v head + log_softmax ----------------
// 256 threads = 4 waves = 64 nodes = 2 graphs. K-SPLIT staging: xst[64][160] holds
// cols [0,160) then [160,320); also reused for h1 (stride 136) and h2 (stride 72).
// LDS ~24 KB -> 5-6 blocks/CU for global-latency hiding.
template<bool BF>
__device__ __forceinline__ void pi_body(
    short* __restrict__ xst, float* __restrict__ rn, float* __restrict__ sg,
    float* __restrict__ pib, float* __restrict__ vb, float* __restrict__ mls,
    const void* __restrict__ x, float* __restrict__ ws, void* __restrict__ out)
{
  const float* in_acc  = ws + OFF_IN_ACC;
  const float* out_acc = ws + OFF_OUT_ACC;
  const float* cnt_in  = ws + OFF_CNT_IN;
  const float* cnt_out = ws + OFF_CNT_OUT;
  const float* p1b = ws + OFF_P1B;
  const float* p2b = ws + OFF_P2B;
  const float* p3b = ws + OFF_P3B;
  const float* p4w = ws + OFF_P4W;
  const float* v1w = ws + OFF_V1W;
  const float* v1b = ws + OFF_V1B;
  const float* v2w = ws + OFF_V2W;
  const float p4b0 = ws[OFF_P4B];
  const float v2b0 = ws[OFF_V2B];

  const int tid = threadIdx.x;
  const int w = tid >> 6, lane = tid & 63;
  const int nn = lane & 15, q = lane >> 4;
  const int nbase = blockIdx.x * 64;
  const int n = tid >> 2, qq = tid & 3;
  const size_t gn = (size_t)(nbase + n);

  // phase 0: per-node reciprocals
  if (tid < 128) {
    int nd = tid >> 1;
    float c = (tid & 1) ? cnt_out[nbase + nd] : cnt_in[nbase + nd];
    rn[nd*2 + (tid & 1)] = __builtin_amdgcn_rcpf(fmaxf(c, 1.f));
  }
  __syncthreads();

  const float rci = rn[n*2], rco = rn[n*2 + 1];
  const float4* iap = (const float4*)(in_acc  + gn * ROWF);
  const float4* oap = (const float4*)(out_acc + gn * ROWF);

  // ---- stage half A: cols [0,160) = x[0..55) + in[0..105) ----
  for (int f = qq; f < 55; f += 4)
    xst[n*160 + f] = (short)f2bf(ldf<BF>(x, gn * 55 + f));
  #pragma unroll
  for (int j4 = 0; j4 < 8; ++j4) {
    int j = qq*32 + j4*4;
    if (j <= 104) {
      float4 v = iap[j >> 2];
      int c = 55 + j;
      xst[n*160 + c] = (short)f2bf(v.x * rci);
      if (j + 1 <= 104) xst[n*160 + c + 1] = (short)f2bf(v.y * rci);
      if (j + 2 <= 104) xst[n*160 + c + 2] = (short)f2bf(v.z * rci);
      if (j + 3 <= 104) xst[n*160 + c + 3] = (short)f2bf(v.w * rci);
    }
  }
  __syncthreads();

  // ---- half A compute: L1 MFMA kk=0..4 + colsums ----
  const short* b1 = (const short*)(ws + OFF_B1);
  f32x4 a1[8];
  #pragma unroll
  for (int T = 0; T < 8; ++T) { float b = p1b[T*16 + nn]; a1[T] = (f32x4){b, b, b, b}; }
  #pragma unroll
  for (int kk = 0; kk < 5; ++kk) {
    short8 af = *(const short8*)&xst[(w*16 + nn) * 160 + kk*32 + q*8];
    #pragma unroll
    for (int T = 0; T < 8; ++T) {
      short8 bfr = *(const short8*)(b1 + ((size_t)(T*10 + kk) * 64 + lane) * 8);
      a1[T] = __builtin_amdgcn_mfma_f32_16x16x32_bf16(af, bfr, a1[T], 0, 0, 0);
    }
  }
  for (int i = tid; i < 320; i += 256) {
    int g = (i >= 160) ? 1 : 0;
    int c = i - g * 160;
    float s = 0.f;
    for (int k = 0; k < 32; ++k) s += bf2f(xst[(g*32 + k) * 160 + c]);
    sg[g*296 + c] = s * (1.f / 32.f);     // col == feature index for cols < 160
  }
  __syncthreads();

  // ---- stage half B: cols [160,320) -> local c-160: in[105..117), out[0..117), zeros ----
  if (qq == 3) {   // in tail
    float4 v = iap[26];   // j=104 chunk, elements 1..3 -> cols 160..162 -> local 0..2
    xst[n*160 + 0] = (short)f2bf(v.y * rci);
    xst[n*160 + 1] = (short)f2bf(v.z * rci);
    xst[n*160 + 2] = (short)f2bf(v.w * rci);
    #pragma unroll
    for (int j = 108; j <= 116; j += 4) {
      float4 u2 = iap[j >> 2];
      int c = j - 105;
      xst[n*160 + c] = (short)f2bf(u2.x * rci);
      if (j + 1 < 117) xst[n*160 + c + 1] = (short)f2bf(u2.y * rci);
      if (j + 2 < 117) xst[n*160 + c + 2] = (short)f2bf(u2.z * rci);
      if (j + 3 < 117) xst[n*160 + c + 3] = (short)f2bf(u2.w * rci);
    }
  }
  #pragma unroll
  for (int j4 = 0; j4 < 8; ++j4) {   // out features: col 172+j -> local 12+j
    int j = qq*32 + j4*4;
    if (j < 117) {
      float4 v = oap[j >> 2];
      int c = 12 + j;
      xst[n*160 + c] = (short)f2bf(v.x * rco);
      if (j + 1 < 117) xst[n*160 + c + 1] = (short)f2bf(v.y * rco);
      if (j + 2 < 117) xst[n*160 + c + 2] = (short)f2bf(v.z * rco);
      if (j + 3 < 117) xst[n*160 + c + 3] = (short)f2bf(v.w * rco);
    }
  }
  for (int c = 129 + qq; c < 160; c += 4) xst[n*160 + c] = 0;   // zero pad cols 289..319
  __syncthreads();

  // ---- half B compute: L1 MFMA kk=5..9 + colsums ----
  #pragma unroll
  for (int kk = 5; kk < 10; ++kk) {
    short8 af = *(const short8*)&xst[(w*16 + nn) * 160 + (kk - 5)*32 + q*8];
    #pragma unroll
    for (int T = 0; T < 8; ++T) {
      short8 bfr = *(const short8*)(b1 + ((size_t)(T*10 + kk) * 64 + lane) * 8);
      a1[T] = __builtin_amdgcn_mfma_f32_16x16x32_bf16(af, bfr, a1[T], 0, 0, 0);
    }
  }
  for (int i = tid; i < 258; i += 256) {
    int g = (i >= 129) ? 1 : 0;
    int c = i - g * 129;
    float s = 0.f;
    for (int k = 0; k < 32; ++k) s += bf2f(xst[(g*32 + k) * 160 + c]);
    sg[g*296 + 160 + c] = s * (1.f / 32.f);   // features 160..288
  }
  __syncthreads();

  // ---- h1 (relu bf16) into xst, stride 136 ----
  #pragma unroll
  for (int T = 0; T < 8; ++T)
    #pragma unroll
    for (int r = 0; r < 4; ++r)
      xst[(w*16 + q*4 + r) * 136 + T*16 + nn] = (short)f2bf(fmaxf(a1[T][r], 0.f));
  __syncthreads();

  // ---- L2 MFMA (reads h1) ----
  const short* b2 = (const short*)(ws + OFF_B2);
  f32x4 a2[4];
  #pragma unroll
  for (int T = 0; T < 4; ++T) { float b = p2b[T*16 + nn]; a2[T] = (f32x4){b, b, b, b}; }
  #pragma unroll
  for (int kk = 0; kk < 4; ++kk) {
    short8 af = *(const short8*)&xst[(w*16 + nn) * 136 + kk*32 + q*8];
    #pragma unroll
    for (int T = 0; T < 4; ++T) {
      short8 bfr = *(const short8*)(b2 + ((size_t)(T*4 + kk) * 64 + lane) * 8);
      a2[T] = __builtin_amdgcn_mfma_f32_16x16x32_bf16(af, bfr, a2[T], 0, 0, 0);
    }
  }
  __syncthreads();   // all h1 reads done before h2 overwrites xst

  // ---- h2 (relu bf16) into xst, stride 72 ----
  #pragma unroll
  for (int T = 0; T < 4; ++T)
    #pragma unroll
    for (int r = 0; r < 4; ++r)
      xst[(w*16 + q*4 + r) * 72 + T*16 + nn] = (short)f2bf(fmaxf(a2[T][r], 0.f));
  __syncthreads();

  // ---- L3 MFMA + L4 dot + v head ----
  const short* b3 = (const short*)(ws + OFF_B3);
  f32x4 a3[2];
  #pragma unroll
  for (int T = 0; T < 2; ++T) { float b = p3b[T*16 + nn]; a3[T] = (f32x4){b, b, b, b}; }
  #pragma unroll
  for (int kk = 0; kk < 2; ++kk) {
    short8 af = *(const short8*)&xst[(w*16 + nn) * 72 + kk*32 + q*8];
    #pragma unroll
    for (int T = 0; T < 2; ++T) {
      short8 bfr = *(const short8*)(b3 + ((size_t)(T*2 + kk) * 64 + lane) * 8);
      a3[T] = __builtin_amdgcn_mfma_f32_16x16x32_bf16(af, bfr, a3[T], 0, 0, 0);
    }
  }
  {
    float w4a = p4w[nn], w4b = p4w[16 + nn];
    float part[4];
    #pragma unroll
    for (int r = 0; r < 4; ++r)
      part[r] = fmaxf(a3[0][r], 0.f) * w4a + fmaxf(a3[1][r], 0.f) * w4b;
    #pragma unroll
    for (int off = 1; off < 16; off <<= 1)
      #pragma unroll
      for (int r = 0; r < 4; ++r) part[r] += __shfl_xor(part[r], off);
    float pv = (nn == 0) ? part[0] : (nn == 1) ? part[1] : (nn == 2) ? part[2] : part[3];
    if (nn < 4) pib[w*16 + q*4 + nn] = pv + p4b0;
  }
  {
    // v head: 256 threads = 2 graphs x 32 units x 4 f-chunks
    int g = tid >> 7;
    int u = (tid >> 2) & 31;
    int ch = tid & 3;
    int f0 = ch * 72;
    int f1 = (ch == 3) ? 289 : f0 + 72;
    float r = (ch == 0) ? v1b[u] : 0.f;
    for (int f = f0; f < f1; ++f) r += sg[g*296 + f] * v1w[f*32 + u];
    r += __shfl_xor(r, 1);
    r += __shfl_xor(r, 2);
    if (ch == 0) vb[g*32 + u] = fmaxf(r, 0.f) * v2w[u];
  }
  __syncthreads();

  // ---- softmax stats + v output ----
  if (tid < 2) {
    float m = -1e30f, s = 0.f, vsum = 0.f;
    for (int k = 0; k < 32; ++k) m = fmaxf(m, pib[tid*32 + k]);
    for (int k = 0; k < 32; ++k) {
      s += __expf(pib[tid*32 + k] - m);
      vsum += vb[tid*32 + k];
    }
    mls[tid*2] = m;
    mls[tid*2 + 1] = __logf(s);
    stf<BF>(out, (size_t)NB * ACT + 2*blockIdx.x + tid, vsum + v2b0);
  }
  __syncthreads();

  // ---- ragged pack + log_softmax ----
  if (tid < 106) {
    int g = (tid >= 53) ? 1 : 0;
    int c = tid - g * 53;
    float val = (c < 32) ? pib[g*32 + c] : -999.f;
    stf<BF>(out, (size_t)(2*blockIdx.x + g) * 53 + c, val - mls[g*2] - mls[g*2 + 1]);
  }
}

__global__ __launch_bounds__(256, 5) void pi_kernel(const int* __restrict__ flag,
                                                    const void* __restrict__ x,
                                                    float* __restrict__ ws,
                                                    void* __restrict__ out)
{
  __shared__ short xst[64 * 160];  // 20480 B; halves staged in sequence; reused for h1/h2
  __shared__ float rn[64 * 2];
  __shared__ float sg[2 * 296];
  __shared__ float pib[64];
  __shared__ float vb[64];
  __shared__ float mls[4];
  if (*flag) pi_body<true>(xst, rn, sg, pib, vb, mls, x, ws, out);
  else       pi_body<false>(xst, rn, sg, pib, vb, mls, x, ws, out);
}

extern "C" void kernel_launch(void* const* d_in, const int* in_sizes, int n_in,
                              void* d_out, int out_size, void* d_ws, size_t ws_size,
                              hipStream_t stream) {
  const void* x        = d_in[0];
  const void* src_num  = d_in[1];
  const void* tgt_num  = d_in[2];
  const int*  tokens   = (const int*)d_in[3];
  const int*  eidx     = (const int*)d_in[4];
  // d_in[5] = batch: repeat(arange(4096), 32); not needed
  PrepPtrs P;
  P.emb  = d_in[6];
  P.wihf = d_in[7];  P.whhf = d_in[8];  P.bfw = d_in[9];
  P.wihb = d_in[10]; P.whhb = d_in[11]; P.bbw = d_in[12];
  P.p1w = d_in[13]; P.p1b = d_in[14];
  P.p2w = d_in[15]; P.p2b = d_in[16];
  P.p3w = d_in[17]; P.p3b = d_in[18];
  P.p4w = d_in[19]; P.p4b = d_in[20];
  P.v1w = d_in[21]; P.v1b = d_in[22];
  P.v2w = d_in[23]; P.v2b = d_in[24];

  float* ws = (float*)d_ws;
  int* flag = (int*)(ws + OFF_FLAG);

  // zero scatter accumulators + counts (~127 MB)
  hipMemsetAsync(d_ws, 0, ZERO_FLOATS * sizeof(float), stream);

  detect_kernel<<<1, 64, 0, stream>>>((const unsigned int*)x, flag);

  prep_kernel<<<302, 256, 0, stream>>>(flag, P, ws);

  lstm_kernel<<<(NE / 32) * 2, 128, 0, stream>>>(flag, tokens, eidx, src_num, tgt_num, ws);

  pi_kernel<<<NN / 64, 256, 0, stream>>>(flag, x, ws, d_out);
}